// Round 9
// baseline (290.809 us; speedup 1.0000x reference)
//
#include <hip/hip_runtime.h>

#define NN 10000    // nodes
#define RR 100      // relations
#define EE 5000     // edges per relation
#define D0 2048
#define D1 128
#define D2 64
#define D3 20
#define NE (RR*EE)  // 500000 edges total

using short8  = __attribute__((ext_vector_type(8))) short;
using float4e = __attribute__((ext_vector_type(4))) float;
using float2v = __attribute__((ext_vector_type(2))) float;

__device__ __forceinline__ unsigned short f2bf(float f) {
  unsigned int u = __float_as_uint(f);
  unsigned int r = u + 0x7fffu + ((u >> 16) & 1u);   // RNE
  return (unsigned short)(r >> 16);
}
__device__ __forceinline__ float bf2f(unsigned short u) {
  return __uint_as_float(((unsigned int)u) << 16);
}
__device__ __forceinline__ unsigned int pk2(float lo, float hi) {
  return ((unsigned int)f2bf(hi) << 16) | (unsigned int)f2bf(lo);
}
__device__ __forceinline__ float bflo(unsigned int u) {
  return __uint_as_float((u & 0xffffu) << 16);
}
__device__ __forceinline__ float bfhi(unsigned int u) {
  return __uint_as_float(u & 0xffff0000u);
}
__device__ __forceinline__ float2v mk2(float a, float b) {
  float2v v; v[0] = a; v[1] = b; return v;
}

// bf16x8 MFMA on uint4-typed fragments
__device__ __forceinline__ float4e bmm(uint4 a, uint4 b, float4e c) {
  return __builtin_amdgcn_mfma_f32_16x16x32_bf16(
      __builtin_bit_cast(short8, a), __builtin_bit_cast(short8, b), c, 0, 0, 0);
}

// ---------------------------------------------------------------------------
// fused prep: deg histogram + all three weight->bf16 fragment-layout packs
// ---------------------------------------------------------------------------
#define W0_SZ 262144   // drug_w frags: c 0..63, nt 0..7
#define W1_SZ 73728    // Wc1 frags:    c 0..35, nt 0..3
#define W2_SZ 18432    // Wc2 frags:    c 0..17, nt 0..1
__global__ void prep_kernel(const int* __restrict__ ei, int* __restrict__ deg,
                            const float* __restrict__ drug_w,
                            unsigned short* __restrict__ Bfw,
                            const float* __restrict__ root1,
                            const float* __restrict__ basis1,
                            unsigned short* __restrict__ Wf1,
                            const float* __restrict__ root2,
                            const float* __restrict__ basis2,
                            unsigned short* __restrict__ Wf2) {
  int gid = blockIdx.x * 256 + threadIdx.x;
  if (gid < NE) {
    int r = gid / EE, e = gid - r * EE;
    int d = ei[r * 2 * EE + EE + e];
    atomicAdd(&deg[r * NN + d], 1);
    return;
  }
  gid -= NE;
  if (gid < W0_SZ) {
    int j = gid & 7, lane = (gid >> 3) & 63, rest = gid >> 9;
    int nt = rest & 7, c = rest >> 3;
    int k = c * 32 + (lane >> 4) * 8 + j;
    int n = nt * 16 + (lane & 15);
    Bfw[gid] = f2bf(drug_w[(size_t)k * 128 + n]);
    return;
  }
  gid -= W0_SZ;
  if (gid < W1_SZ) {
    int j = gid & 7, lane = (gid >> 3) & 63, rest = gid >> 9;
    int nt = rest & 3, c = rest >> 2;
    int k = c * 32 + (lane >> 4) * 8 + j;
    int o = nt * 16 + (lane & 15);
    float v = (k < 128) ? root1[k * 64 + o] : basis1[(k - 128) * 64 + o];
    Wf1[gid] = f2bf(v);
    return;
  }
  gid -= W1_SZ;
  if (gid < W2_SZ) {
    int j = gid & 7, lane = (gid >> 3) & 63, rest = gid >> 9;
    int nt = rest & 1, c = rest >> 1;
    int k = c * 32 + (lane >> 4) * 8 + j;
    int cc = nt * 16 + (lane & 15);
    float v = 0.f;
    if (cc < 20) v = (k < 64) ? root2[k * 20 + cc] : basis2[(k - 64) * 20 + cc];
    Wf2[gid] = f2bf(v);
  }
}

// ---------------------------------------------------------------------------
// single-pass scan
// ---------------------------------------------------------------------------
__global__ __launch_bounds__(1024) void scan_kernel(const int* __restrict__ cnt,
                                                    int* __restrict__ off,
                                                    int* __restrict__ cur) {
  __shared__ int wsum[16];
  const int tid = threadIdx.x;
  const int wv = tid >> 6, lane = tid & 63;
  const bool act = tid < 1000;
  int loc[10];
  int s = 0;
  if (act) {
#pragma unroll
    for (int i = 0; i < 10; i++) { loc[i] = cnt[tid * 10 + i]; s += loc[i]; }
  }
  int ws = s;
#pragma unroll
  for (int d = 1; d < 64; d <<= 1) {
    int t = __shfl_up(ws, d, 64);
    if (lane >= d) ws += t;
  }
  if (lane == 63) wsum[wv] = ws;
  __syncthreads();
  if (wv == 0) {
    int w = (lane < 16) ? wsum[lane] : 0;
#pragma unroll
    for (int d = 1; d < 16; d <<= 1) {
      int t = __shfl_up(w, d, 64);
      if (lane >= d) w += t;
    }
    if (lane < 16) wsum[lane] = w;
  }
  __syncthreads();
  int excl = (wv ? wsum[wv - 1] : 0) + ws - s;
  if (act) {
    int run = excl;
#pragma unroll
    for (int i = 0; i < 10; i++) {
      off[tid * 10 + i] = run;
      cur[tid * 10 + i] = run;
      run += loc[i];
    }
  }
  if (tid == 1023) off[NN] = excl;   // s==0 for tid>=1000 -> excl == total
}

// rec[p] = (r<<14)|src -- 4B record; esc now comes from invT at agg time
__global__ void scatter_kernel(const int* __restrict__ ei,
                               int* __restrict__ cur, int* __restrict__ rec) {
  int gid = blockIdx.x * 256 + threadIdx.x;
  if (gid >= NE) return;
  int r = gid / EE, e = gid - r * EE;
  int s = ei[r * 2 * EE + e];
  int d = ei[r * 2 * EE + EE + e];
  int p = atomicAdd(&cur[d], 1);
  rec[p] = (r << 14) | s;
}

// ---------------------------------------------------------------------------
// gemm0cnt: blocks 0..312 = gemm0 (M=32, N=128); blocks 313..352 = cnt +
// invT[n][r] = 1/max(deg[r][n],1) (float4-vectorized per-node rows).
// ---------------------------------------------------------------------------
__global__ __launch_bounds__(256) void gemm0cnt(
    const float* __restrict__ A, const unsigned short* __restrict__ Bfw,
    unsigned short* __restrict__ xb, const int* __restrict__ deg,
    int* __restrict__ cnt, float* __restrict__ invT) {
  if (blockIdx.x >= 313) {
    int n = (blockIdx.x - 313) * 256 + threadIdx.x;
    if (n < NN) {
      int s = 0;
      for (int r0 = 0; r0 < RR; r0 += 4) {
        float iv[4];
#pragma unroll
        for (int q = 0; q < 4; q++) {
          int dv = deg[(r0 + q) * NN + n];
          s += dv;
          iv[q] = 1.0f / fmaxf((float)dv, 1.0f);
        }
        *(float4*)&invT[(size_t)n * RR + r0] =
            make_float4(iv[0], iv[1], iv[2], iv[3]);
      }
      cnt[n] = s;
    }
    return;
  }
  __shared__ unsigned short As[2][32 * 128];
  const int tid = threadIdx.x;
  const int nw = tid >> 6, lane = tid & 63;
  const int lrow = lane & 15, quad = lane >> 4;
  const int m0 = blockIdx.x * 32;

  const int rb = tid >> 5, li = tid & 31;
  int rg[4], wo[4];
#pragma unroll
  for (int j = 0; j < 4; j++) {
    int r = rb + 8 * j;
    int g = m0 + r;
    rg[j] = g < NN ? g : NN - 1;
    wo[j] = r * 128 + (((li >> 1) ^ (r & 15)) & 15) * 8 + (li & 1) * 4;
  }

  const uint4* Bq = (const uint4*)Bfw;
  float4 rAe[4], rAo[4];
  uint4 B0[8], B1[8];
  float4e acc[2][2];
#pragma unroll
  for (int mt = 0; mt < 2; mt++)
#pragma unroll
    for (int i = 0; i < 2; i++) {
      acc[mt][i][0] = 0.f; acc[mt][i][1] = 0.f;
      acc[mt][i][2] = 0.f; acc[mt][i][3] = 0.f;
    }

#define LDA(ra, t)                                                   \
  { int tc = (t) > 15 ? 15 : (t);                                    \
    _Pragma("unroll")                                                \
    for (int j = 0; j < 4; j++)                                      \
      ra[j] = *(const float4*)(A + (size_t)rg[j] * D0 + tc * 128 + li * 4); }
#define LDB(B, t)                                                    \
  { int tc = (t) > 15 ? 15 : (t);                                    \
    _Pragma("unroll")                                                \
    for (int kk = 0; kk < 4; kk++) {                                 \
      B[2 * kk]     = Bq[((tc * 4 + kk) * 8 + 2 * nw) * 64 + lane];  \
      B[2 * kk + 1] = Bq[((tc * 4 + kk) * 8 + 2 * nw + 1) * 64 + lane]; } }
#define STA(buf, ra)                                                 \
  { _Pragma("unroll")                                                \
    for (int j = 0; j < 4; j++) {                                    \
      uint2 u; u.x = pk2(ra[j].x, ra[j].y); u.y = pk2(ra[j].z, ra[j].w); \
      *(uint2*)&As[buf][wo[j]] = u; } }
#define CMP(buf, B)                                                  \
  { _Pragma("unroll")                                                \
    for (int kk = 0; kk < 4; kk++) {                                 \
      _Pragma("unroll")                                              \
      for (int mt = 0; mt < 2; mt++) {                               \
        uint4 af = *(const uint4*)&As[buf][(mt * 16 + lrow) * 128 +  \
                                           (((kk * 4 + quad) ^ lrow) & 15) * 8]; \
        acc[mt][0] = bmm(af, B[2 * kk], acc[mt][0]);                 \
        acc[mt][1] = bmm(af, B[2 * kk + 1], acc[mt][1]); } } }

  LDA(rAe, 0); LDB(B0, 0);
  LDA(rAo, 1);
  STA(0, rAe);
  LDB(B1, 1);
  LDA(rAe, 2);
  __syncthreads();

  for (int t = 0; t < 16; t += 2) {
    STA(1, rAo);
    LDA(rAo, t + 3);
    CMP(0, B0);
    LDB(B0, t + 2);
    __syncthreads();
    STA(0, rAe);
    LDA(rAe, t + 4);
    CMP(1, B1);
    LDB(B1, t + 3);
    __syncthreads();
  }
#undef LDA
#undef LDB
#undef STA
#undef CMP

  const int c0 = nw * 32 + lrow;
#pragma unroll
  for (int mt = 0; mt < 2; mt++) {
#pragma unroll
    for (int j = 0; j < 4; j++) {
      int r = m0 + mt * 16 + quad * 4 + j;
      if (r < NN) {
        xb[(size_t)r * D1 + c0]      = f2bf(acc[mt][0][j]);
        xb[(size_t)r * D1 + c0 + 16] = f2bf(acc[mt][1][j]);
      }
    }
  }
}

// ---------------------------------------------------------------------------
// agg1e: A1b[n, b*128+i] = bf16( sum_{e->n} esc_e*comp1[r_e,b]*x[src_e,i] )
// one wave per node; rec (4B) via scalarized uniform loads; esc from
// wave-uniform invT row (SGPR-based s_load); comp rows likewise.
// ---------------------------------------------------------------------------
__global__ __launch_bounds__(256) void agg1e_kernel(
    const unsigned short* __restrict__ xb, const int* __restrict__ off,
    const int* __restrict__ rec, const float* __restrict__ invT,
    const float* __restrict__ comp, unsigned short* __restrict__ A1b) {
  const int tid = threadIdx.x;
  const int wv = tid >> 6, lane = tid & 63;
  const int n = blockIdx.x * 4 + wv;
  if (n >= NN) return;
  const float* ninv = &invT[(size_t)n * RR];
  float2v acc[8];
#pragma unroll
  for (int b = 0; b < 8; b++) { acc[b][0] = 0.f; acc[b][1] = 0.f; }
  const int beg = __builtin_amdgcn_readfirstlane(off[n]);
  const int end = __builtin_amdgcn_readfirstlane(off[n + 1]);
  int idx = beg;
  for (; idx + 7 < end; idx += 8) {
    int rc[8]; unsigned int xv[8];
#pragma unroll
    for (int u = 0; u < 8; u++)
      rc[u] = __builtin_amdgcn_readfirstlane(rec[idx + u]);
#pragma unroll
    for (int u = 0; u < 8; u++)
      xv[u] = *(const unsigned int*)&xb[(size_t)(rc[u] & 16383) * D1 + lane * 2];
#pragma unroll
    for (int u = 0; u < 8; u++) {
      int r = rc[u] >> 14;
      const float* cb = &comp[r * 8];
      float sc = ninv[r];
      float2v sx = mk2(sc * bflo(xv[u]), sc * bfhi(xv[u]));
#pragma unroll
      for (int b = 0; b < 8; b++)
        acc[b] = __builtin_elementwise_fma(mk2(cb[b], cb[b]), sx, acc[b]);
    }
  }
  for (; idx < end; idx++) {
    int rc = __builtin_amdgcn_readfirstlane(rec[idx]);
    int r = rc >> 14;
    unsigned int xv = *(const unsigned int*)&xb[(size_t)(rc & 16383) * D1 + lane * 2];
    const float* cb = &comp[r * 8];
    float sc = ninv[r];
    float2v sx = mk2(sc * bflo(xv), sc * bfhi(xv));
#pragma unroll
    for (int b = 0; b < 8; b++)
      acc[b] = __builtin_elementwise_fma(mk2(cb[b], cb[b]), sx, acc[b]);
  }
#pragma unroll
  for (int b = 0; b < 8; b++) {
    ushort2 o; o.x = f2bf(acc[b][0]); o.y = f2bf(acc[b][1]);
    *(ushort2*)&A1b[(size_t)n * 1024 + b * 128 + lane * 2] = o;
  }
}

// ---------------------------------------------------------------------------
// agg2e: one wave per node; same scalarized structure; esc from invT row.
// ---------------------------------------------------------------------------
__global__ __launch_bounds__(256) void agg2e_kernel(
    const unsigned short* __restrict__ hb, const int* __restrict__ off,
    const int* __restrict__ rec, const float* __restrict__ invT,
    const float* __restrict__ comp, unsigned short* __restrict__ A2b) {
  const int tid = threadIdx.x;
  const int wv = tid >> 6, lane = tid & 63;
  const int n = blockIdx.x * 4 + wv;
  if (n >= NN) return;
  const float* ninv = &invT[(size_t)n * RR];
  float acc[8];
#pragma unroll
  for (int b = 0; b < 8; b++) acc[b] = 0.f;
  const int beg = __builtin_amdgcn_readfirstlane(off[n]);
  const int end = __builtin_amdgcn_readfirstlane(off[n + 1]);
  int idx = beg;
  for (; idx + 7 < end; idx += 8) {
    int rc[8]; float hv[8];
#pragma unroll
    for (int u = 0; u < 8; u++)
      rc[u] = __builtin_amdgcn_readfirstlane(rec[idx + u]);
#pragma unroll
    for (int u = 0; u < 8; u++)
      hv[u] = bf2f(hb[(size_t)(rc[u] & 16383) * D2 + lane]);
#pragma unroll
    for (int u = 0; u < 8; u++) {
      int r = rc[u] >> 14;
      const float* cb = &comp[r * 8];
      float sh = ninv[r] * hv[u];
#pragma unroll
      for (int b = 0; b < 8; b++) acc[b] = fmaf(cb[b], sh, acc[b]);
    }
  }
  for (; idx < end; idx++) {
    int rc = __builtin_amdgcn_readfirstlane(rec[idx]);
    int r = rc >> 14;
    float hv = bf2f(hb[(size_t)(rc & 16383) * D2 + lane]);
    const float* cb = &comp[r * 8];
    float sh = ninv[r] * hv;
#pragma unroll
    for (int b = 0; b < 8; b++) acc[b] = fmaf(cb[b], sh, acc[b]);
  }
#pragma unroll
  for (int b = 0; b < 8; b++)
    A2b[(size_t)n * 512 + b * 64 + lane] = f2bf(acc[b]);
}

// ---------------------------------------------------------------------------
// hlayer_v4: hb = bf16(relu([xb|A1b](K=1152) @ Wc1 + bias1))
// ---------------------------------------------------------------------------
__global__ __launch_bounds__(256) void hlayer_v4(
    const unsigned short* __restrict__ xb, const unsigned short* __restrict__ A1b,
    const unsigned short* __restrict__ Wf, const float* __restrict__ bias1,
    unsigned short* __restrict__ hb) {
  __shared__ unsigned short Hs[2][32 * 128];
  const int tid = threadIdx.x;
  const int wv = tid >> 6, lane = tid & 63;
  const int lrow = lane & 15, quad = lane >> 4;
  const int m0 = blockIdx.x * 32;
  const int mt = wv >> 1, nb = (wv & 1) * 2;

  int rgr[2], su4[2], sph[2];
#pragma unroll
  for (int p = 0; p < 2; p++) {
    int idx = tid + p * 256;
    int r = idx >> 4, u = idx & 15;
    int g = m0 + r;
    rgr[p] = g < NN ? g : NN - 1;
    su4[p] = u;
    sph[p] = r * 128 + ((u ^ (r & 15)) & 15) * 8;
  }

  const uint4* Bq = (const uint4*)Wf;
  uint4 rAe[2], rAo[2];
  uint4 B0[8], B1[8];
  float4e acc[2];
#pragma unroll
  for (int i = 0; i < 2; i++) {
    acc[i][0] = 0.f; acc[i][1] = 0.f; acc[i][2] = 0.f; acc[i][3] = 0.f;
  }

#define H_LDA(ra, t)                                                       \
  { int tc = (t) > 8 ? 8 : (t);                                            \
    _Pragma("unroll")                                                      \
    for (int p = 0; p < 2; p++) {                                          \
      const unsigned short* sp = (tc == 0)                                 \
          ? (xb + (size_t)rgr[p] * D1 + su4[p] * 8)                        \
          : (A1b + (size_t)rgr[p] * 1024 + (tc - 1) * 128 + su4[p] * 8);   \
      ra[p] = *(const uint4*)sp; } }
#define H_LDB(B, t)                                                        \
  { int tc = (t) > 8 ? 8 : (t);                                            \
    _Pragma("unroll")                                                      \
    for (int kk = 0; kk < 4; kk++) {                                       \
      int c = tc * 4 + kk;                                                 \
      B[2 * kk]     = Bq[(c * 4 + nb) * 64 + lane];                        \
      B[2 * kk + 1] = Bq[(c * 4 + nb + 1) * 64 + lane]; } }
#define H_STA(buf, ra)                                                     \
  { _Pragma("unroll")                                                      \
    for (int p = 0; p < 2; p++) *(uint4*)&Hs[buf][sph[p]] = ra[p]; }
#define H_CMP(buf, B)                                                      \
  { _Pragma("unroll")                                                      \
    for (int kk = 0; kk < 4; kk++) {                                       \
      uint4 af = *(const uint4*)&Hs[buf][(mt * 16 + lrow) * 128 +          \
                                         (((kk * 4 + quad) ^ lrow) & 15) * 8]; \
      acc[0] = bmm(af, B[2 * kk], acc[0]);                                 \
      acc[1] = bmm(af, B[2 * kk + 1], acc[1]); } }

  H_LDA(rAe, 0); H_LDB(B0, 0);
  H_LDA(rAo, 1);
  H_STA(0, rAe);
  H_LDB(B1, 1);
  H_LDA(rAe, 2);
  __syncthreads();

  for (int t = 0; t < 8; t += 2) {
    H_STA(1, rAo);
    H_LDA(rAo, t + 3);
    H_CMP(0, B0);
    H_LDB(B0, t + 2);
    __syncthreads();
    H_STA(0, rAe);
    H_LDA(rAe, t + 4);
    H_CMP(1, B1);
    H_LDB(B1, t + 3);
    __syncthreads();
  }
  H_CMP(0, B0);                                   // tile 8
#undef H_LDA
#undef H_LDB
#undef H_STA
#undef H_CMP

#pragma unroll
  for (int ntl = 0; ntl < 2; ntl++) {
    int col = (nb + ntl) * 16 + lrow;
    float bv = bias1[col];
#pragma unroll
    for (int j = 0; j < 4; j++) {
      int r = m0 + mt * 16 + quad * 4 + j;
      if (r < NN)
        hb[(size_t)r * D2 + col] = f2bf(fmaxf(acc[ntl][j] + bv, 0.f));
    }
  }
}

// ---------------------------------------------------------------------------
// out_v4: out = [hb|A2b](K=576) @ Wc2 + bias2
// ---------------------------------------------------------------------------
__global__ __launch_bounds__(128) void out_v4(
    const unsigned short* __restrict__ hb, const unsigned short* __restrict__ A2b,
    const unsigned short* __restrict__ Wf, const float* __restrict__ bias2,
    float* __restrict__ out) {
  __shared__ unsigned short Os[2][32 * 64];
  const int tid = threadIdx.x;
  const int wv = tid >> 6, lane = tid & 63;
  const int lrow = lane & 15, quad = lane >> 4;
  const int m0 = blockIdx.x * 32;

  int rgr[2], su4[2], sph[2];
#pragma unroll
  for (int p = 0; p < 2; p++) {
    int idx = tid + p * 128;
    int r = idx >> 3, u = idx & 7;
    int g = m0 + r;
    rgr[p] = g < NN ? g : NN - 1;
    su4[p] = u;
    sph[p] = r * 64 + ((u ^ (r & 7)) & 7) * 8;
  }

  const uint4* Bq = (const uint4*)Wf;
  uint4 rAe[2], rAo[2];
  uint4 B0[4], B1[4];
  float4e acc[2];
#pragma unroll
  for (int i = 0; i < 2; i++) {
    acc[i][0] = 0.f; acc[i][1] = 0.f; acc[i][2] = 0.f; acc[i][3] = 0.f;
  }

#define O_LDA(ra, t)                                                       \
  { int tc = (t) > 8 ? 8 : (t);                                            \
    _Pragma("unroll")                                                      \
    for (int p = 0; p < 2; p++) {                                          \
      const unsigned short* sp = (tc == 0)                                 \
          ? (hb + (size_t)rgr[p] * D2 + su4[p] * 8)                        \
          : (A2b + (size_t)rgr[p] * 512 + (tc - 1) * 64 + su4[p] * 8);     \
      ra[p] = *(const uint4*)sp; } }
#define O_LDB(B, t)                                                        \
  { int tc = (t) > 8 ? 8 : (t);                                            \
    _Pragma("unroll")                                                      \
    for (int kk = 0; kk < 2; kk++) {                                       \
      int c = tc * 2 + kk;                                                 \
      B[2 * kk]     = Bq[(c * 2) * 64 + lane];                             \
      B[2 * kk + 1] = Bq[(c * 2 + 1) * 64 + lane]; } }
#define O_STA(buf, ra)                                                     \
  { _Pragma("unroll")                                                      \
    for (int p = 0; p < 2; p++) *(uint4*)&Os[buf][sph[p]] = ra[p]; }
#define O_CMP(buf, B)                                                      \
  { _Pragma("unroll")                                                      \
    for (int kk = 0; kk < 2; kk++) {                                       \
      uint4 af = *(const uint4*)&Os[buf][(wv * 16 + lrow) * 64 +           \
                                         (((kk * 4 + quad) ^ lrow) & 7) * 8]; \
      acc[0] = bmm(af, B[2 * kk], acc[0]);                                 \
      acc[1] = bmm(af, B[2 * kk + 1], acc[1]); } }

  O_LDA(rAe, 0); O_LDB(B0, 0);
  O_LDA(rAo, 1);
  O_STA(0, rAe);
  O_LDB(B1, 1);
  O_LDA(rAe, 2);
  __syncthreads();

  for (int t = 0; t < 8; t += 2) {
    O_STA(1, rAo);
    O_LDA(rAo, t + 3);
    O_CMP(0, B0);
    O_LDB(B0, t + 2);
    __syncthreads();
    O_STA(0, rAe);
    O_LDA(rAe, t + 4);
    O_CMP(1, B1);
    O_LDB(B1, t + 3);
    __syncthreads();
  }
  O_CMP(0, B0);                                   // tile 8
#undef O_LDA
#undef O_LDB
#undef O_STA
#undef O_CMP

#pragma unroll
  for (int ntl = 0; ntl < 2; ntl++) {
    int col = ntl * 16 + lrow;
    if (col < D3) {
      float bv = bias2[col];
#pragma unroll
      for (int j = 0; j < 4; j++) {
        int r = m0 + wv * 16 + quad * 4 + j;
        if (r < NN)
          out[(size_t)r * D3 + col] = acc[ntl][j] + bv;
      }
    }
  }
}

// ---------------------------------------------------------------------------
extern "C" void kernel_launch(void* const* d_in, const int* in_sizes, int n_in,
                              void* d_out, int out_size, void* d_ws,
                              size_t ws_size, hipStream_t stream) {
  const float* x_drug = (const float*)d_in[0];
  const float* drug_w = (const float*)d_in[1];
  const int*   ei     = (const int*)d_in[2];
  const float* basis1 = (const float*)d_in[3];
  const float* comp1  = (const float*)d_in[4];
  const float* root1  = (const float*)d_in[5];
  const float* bias1  = (const float*)d_in[6];
  const float* basis2 = (const float*)d_in[7];
  const float* comp2  = (const float*)d_in[8];
  const float* root2  = (const float*)d_in[9];
  const float* bias2  = (const float*)d_in[10];
  float* out = (float*)d_out;

  float* ws = (float*)d_ws;
  int*   deg  = (int*)ws;                          // 1,000,000
  int*   cnt  = deg + 1000000;                     // 10,016
  int*   off  = cnt + 10016;                       // 10,016
  int*   cur  = off + 10016;                       // 10,016
  int*   rec  = cur + 10016;                       // 500,000 (4B records)
  float* invT = (float*)(rec + 500000);            // 1,000,000 ([n][r] rows)
  unsigned short* xb   = (unsigned short*)(invT + 1000000);        // 640,000 f
  unsigned short* hb   = (unsigned short*)((float*)xb + 640000);   // 320,000 f
  unsigned short* Bfw  = (unsigned short*)((float*)hb + 320000);   // 131,072 f
  unsigned short* Wf1  = (unsigned short*)((float*)Bfw + 131072);  // 36,864 f
  unsigned short* Wf2  = (unsigned short*)((float*)Wf1 + 36864);   // 9,216 f
  float* R1 = (float*)Wf2 + 9216;                  // aggregation buffers
  unsigned short* A1b = (unsigned short*)R1;       // 10,000 x 1024 bf16
  unsigned short* A2b = (unsigned short*)R1;       // aliases A1b (after hlayer)

  hipMemsetAsync(deg, 0, (size_t)1000000 * 4, stream);

  // CSR build + weight prep (fused first pass)
  prep_kernel<<<(NE + W0_SZ + W1_SZ + W2_SZ + 255) / 256, 256, 0, stream>>>(
      ei, deg, drug_w, Bfw, root1, basis1, Wf1, root2, basis2, Wf2);

  // gemm0 (needs Bfw) overlapped with cnt+invT (needs deg) -- both from prep
  gemm0cnt<<<313 + 40, 256, 0, stream>>>(x_drug, Bfw, xb, deg, cnt, invT);

  scan_kernel<<<1, 1024, 0, stream>>>(cnt, off, cur);
  scatter_kernel<<<(NE + 255) / 256, 256, 0, stream>>>(ei, cur, rec);

  // layer 1
  agg1e_kernel<<<(NN + 3) / 4, 256, 0, stream>>>(xb, off, rec, invT, comp1, A1b);
  hlayer_v4<<<(NN + 31) / 32, 256, 0, stream>>>(xb, A1b, Wf1, bias1, hb);

  // layer 2
  agg2e_kernel<<<(NN + 3) / 4, 256, 0, stream>>>(hb, off, rec, invT, comp2, A2b);
  out_v4<<<(NN + 31) / 32, 128, 0, stream>>>(hb, A2b, Wf2, bias2, out);
}

// Round 10
// 288.984 us; speedup vs baseline: 1.0063x; 1.0063x over previous
//
#include <hip/hip_runtime.h>

#define NN 10000    // nodes
#define RR 100      // relations
#define EE 5000     // edges per relation
#define D0 2048
#define D1 128
#define D2 64
#define D3 20
#define NE (RR*EE)  // 500000 edges total

using short8  = __attribute__((ext_vector_type(8))) short;
using float4e = __attribute__((ext_vector_type(4))) float;
using float2v = __attribute__((ext_vector_type(2))) float;

__device__ __forceinline__ unsigned short f2bf(float f) {
  unsigned int u = __float_as_uint(f);
  unsigned int r = u + 0x7fffu + ((u >> 16) & 1u);   // RNE
  return (unsigned short)(r >> 16);
}
__device__ __forceinline__ float bf2f(unsigned short u) {
  return __uint_as_float(((unsigned int)u) << 16);
}
__device__ __forceinline__ unsigned int pk2(float lo, float hi) {
  return ((unsigned int)f2bf(hi) << 16) | (unsigned int)f2bf(lo);
}
__device__ __forceinline__ float bflo(unsigned int u) {
  return __uint_as_float((u & 0xffffu) << 16);
}
__device__ __forceinline__ float bfhi(unsigned int u) {
  return __uint_as_float(u & 0xffff0000u);
}
__device__ __forceinline__ float2v mk2(float a, float b) {
  float2v v; v[0] = a; v[1] = b; return v;
}

// bf16x8 MFMA on uint4-typed fragments
__device__ __forceinline__ float4e bmm(uint4 a, uint4 b, float4e c) {
  return __builtin_amdgcn_mfma_f32_16x16x32_bf16(
      __builtin_bit_cast(short8, a), __builtin_bit_cast(short8, b), c, 0, 0, 0);
}

// ---------------------------------------------------------------------------
// fused prep: deg histogram + all three weight->bf16 fragment-layout packs
// ---------------------------------------------------------------------------
#define W0_SZ 262144   // drug_w frags: c 0..63, nt 0..7
#define W1_SZ 73728    // Wc1 frags:    c 0..35, nt 0..3
#define W2_SZ 18432    // Wc2 frags:    c 0..17, nt 0..1
__global__ void prep_kernel(const int* __restrict__ ei, int* __restrict__ deg,
                            const float* __restrict__ drug_w,
                            unsigned short* __restrict__ Bfw,
                            const float* __restrict__ root1,
                            const float* __restrict__ basis1,
                            unsigned short* __restrict__ Wf1,
                            const float* __restrict__ root2,
                            const float* __restrict__ basis2,
                            unsigned short* __restrict__ Wf2) {
  int gid = blockIdx.x * 256 + threadIdx.x;
  if (gid < NE) {
    int r = gid / EE, e = gid - r * EE;
    int d = ei[r * 2 * EE + EE + e];
    atomicAdd(&deg[r * NN + d], 1);
    return;
  }
  gid -= NE;
  if (gid < W0_SZ) {
    int j = gid & 7, lane = (gid >> 3) & 63, rest = gid >> 9;
    int nt = rest & 7, c = rest >> 3;
    int k = c * 32 + (lane >> 4) * 8 + j;
    int n = nt * 16 + (lane & 15);
    Bfw[gid] = f2bf(drug_w[(size_t)k * 128 + n]);
    return;
  }
  gid -= W0_SZ;
  if (gid < W1_SZ) {
    int j = gid & 7, lane = (gid >> 3) & 63, rest = gid >> 9;
    int nt = rest & 3, c = rest >> 2;
    int k = c * 32 + (lane >> 4) * 8 + j;
    int o = nt * 16 + (lane & 15);
    float v = (k < 128) ? root1[k * 64 + o] : basis1[(k - 128) * 64 + o];
    Wf1[gid] = f2bf(v);
    return;
  }
  gid -= W1_SZ;
  if (gid < W2_SZ) {
    int j = gid & 7, lane = (gid >> 3) & 63, rest = gid >> 9;
    int nt = rest & 1, c = rest >> 1;
    int k = c * 32 + (lane >> 4) * 8 + j;
    int cc = nt * 16 + (lane & 15);
    float v = 0.f;
    if (cc < 20) v = (k < 64) ? root2[k * 20 + cc] : basis2[(k - 64) * 20 + cc];
    Wf2[gid] = f2bf(v);
  }
}

// ---------------------------------------------------------------------------
// single-pass scan
// ---------------------------------------------------------------------------
__global__ __launch_bounds__(1024) void scan_kernel(const int* __restrict__ cnt,
                                                    int* __restrict__ off,
                                                    int* __restrict__ cur) {
  __shared__ int wsum[16];
  const int tid = threadIdx.x;
  const int wv = tid >> 6, lane = tid & 63;
  const bool act = tid < 1000;
  int loc[10];
  int s = 0;
  if (act) {
#pragma unroll
    for (int i = 0; i < 10; i++) { loc[i] = cnt[tid * 10 + i]; s += loc[i]; }
  }
  int ws = s;
#pragma unroll
  for (int d = 1; d < 64; d <<= 1) {
    int t = __shfl_up(ws, d, 64);
    if (lane >= d) ws += t;
  }
  if (lane == 63) wsum[wv] = ws;
  __syncthreads();
  if (wv == 0) {
    int w = (lane < 16) ? wsum[lane] : 0;
#pragma unroll
    for (int d = 1; d < 16; d <<= 1) {
      int t = __shfl_up(w, d, 64);
      if (lane >= d) w += t;
    }
    if (lane < 16) wsum[lane] = w;
  }
  __syncthreads();
  int excl = (wv ? wsum[wv - 1] : 0) + ws - s;
  if (act) {
    int run = excl;
#pragma unroll
    for (int i = 0; i < 10; i++) {
      off[tid * 10 + i] = run;
      cur[tid * 10 + i] = run;
      run += loc[i];
    }
  }
  if (tid == 1023) off[NN] = excl;   // s==0 for tid>=1000 -> excl == total
}

// re[p] = { (r<<14)|src , bits(1/max(deg,1)) }  -- one 8B record per edge
__global__ void scatter_kernel(const int* __restrict__ ei,
                               const int* __restrict__ deg,
                               int* __restrict__ cur, int2* __restrict__ re) {
  int gid = blockIdx.x * 256 + threadIdx.x;
  if (gid >= NE) return;
  int r = gid / EE, e = gid - r * EE;
  int s = ei[r * 2 * EE + e];
  int d = ei[r * 2 * EE + EE + e];
  int p = atomicAdd(&cur[d], 1);
  float escv = 1.0f / fmaxf((float)deg[r * NN + d], 1.0f);
  re[p] = make_int2((r << 14) | s, __float_as_int(escv));
}

// ---------------------------------------------------------------------------
// gemm0cnt: blocks 0..624 = gemm0 (M=16, N=128, 4 waves -> 2.4 blocks/CU so
// cross-block overlap hides each block's barrier drains); blocks 625..664 =
// cnt (node total degree) riding free.
// ---------------------------------------------------------------------------
__global__ __launch_bounds__(256) void gemm0cnt(
    const float* __restrict__ A, const unsigned short* __restrict__ Bfw,
    unsigned short* __restrict__ xb, const int* __restrict__ deg,
    int* __restrict__ cnt) {
  if (blockIdx.x >= 625) {
    int n = (blockIdx.x - 625) * 256 + threadIdx.x;
    if (n < NN) {
      int s = 0;
      for (int r = 0; r < RR; r++) s += deg[r * NN + n];
      cnt[n] = s;
    }
    return;
  }
  __shared__ unsigned short As[2][16 * 128];
  const int tid = threadIdx.x;
  const int nw = tid >> 6, lane = tid & 63;
  const int lrow = lane & 15, quad = lane >> 4;
  const int m0 = blockIdx.x * 16;                  // 625*16 == 10000 exact

  // staging: thread covers rows rb+8j (j=0..1), 1 float4 per row (li*16B)
  const int rb = tid >> 5, li = tid & 31;
  int rg[2], wo[2];
#pragma unroll
  for (int j = 0; j < 2; j++) {
    int r = rb + 8 * j;
    rg[j] = m0 + r;
    wo[j] = r * 128 + (((li >> 1) ^ (r & 15)) & 15) * 8 + (li & 1) * 4;
  }

  const uint4* Bq = (const uint4*)Bfw;
  float4 rAe[2], rAo[2];
  uint4 B0[8], B1[8];
  float4e acc0 = {0.f, 0.f, 0.f, 0.f};
  float4e acc1 = {0.f, 0.f, 0.f, 0.f};

#define LDA(ra, t)                                                   \
  { int tc = (t) > 15 ? 15 : (t);                                    \
    _Pragma("unroll")                                                \
    for (int j = 0; j < 2; j++)                                      \
      ra[j] = *(const float4*)(A + (size_t)rg[j] * D0 + tc * 128 + li * 4); }
#define LDB(B, t)                                                    \
  { int tc = (t) > 15 ? 15 : (t);                                    \
    _Pragma("unroll")                                                \
    for (int kk = 0; kk < 4; kk++) {                                 \
      B[2 * kk]     = Bq[((tc * 4 + kk) * 8 + 2 * nw) * 64 + lane];  \
      B[2 * kk + 1] = Bq[((tc * 4 + kk) * 8 + 2 * nw + 1) * 64 + lane]; } }
#define STA(buf, ra)                                                 \
  { _Pragma("unroll")                                                \
    for (int j = 0; j < 2; j++) {                                    \
      uint2 u; u.x = pk2(ra[j].x, ra[j].y); u.y = pk2(ra[j].z, ra[j].w); \
      *(uint2*)&As[buf][wo[j]] = u; } }
#define CMP(buf, B)                                                  \
  { _Pragma("unroll")                                                \
    for (int kk = 0; kk < 4; kk++) {                                 \
      uint4 af = *(const uint4*)&As[buf][lrow * 128 +                \
                                         (((kk * 4 + quad) ^ lrow) & 15) * 8]; \
      acc0 = bmm(af, B[2 * kk], acc0);                               \
      acc1 = bmm(af, B[2 * kk + 1], acc1); } }

  LDA(rAe, 0); LDB(B0, 0);
  LDA(rAo, 1);
  STA(0, rAe);
  LDB(B1, 1);
  LDA(rAe, 2);
  __syncthreads();

  for (int t = 0; t < 16; t += 2) {
    STA(1, rAo);
    LDA(rAo, t + 3);
    CMP(0, B0);
    LDB(B0, t + 2);
    __syncthreads();
    STA(0, rAe);
    LDA(rAe, t + 4);
    CMP(1, B1);
    LDB(B1, t + 3);
    __syncthreads();
  }
#undef LDA
#undef LDB
#undef STA
#undef CMP

  const int c0 = nw * 32 + lrow;
#pragma unroll
  for (int j = 0; j < 4; j++) {
    int r = m0 + quad * 4 + j;
    xb[(size_t)r * D1 + c0]      = f2bf(acc0[j]);
    xb[(size_t)r * D1 + c0 + 16] = f2bf(acc1[j]);
  }
}

// ---------------------------------------------------------------------------
// agg1e: A1b[n, b*128+i] = bf16( sum_{e->n} esc_e*comp1[r_e,b]*x[src_e,i] )
// one wave per node; re records (8B, rec+esc packed) via scalarized uniform
// loads (s_load_dwordx8 per 4 records); comp rows via SGPR-based loads.
// ---------------------------------------------------------------------------
__global__ __launch_bounds__(256) void agg1e_kernel(
    const unsigned short* __restrict__ xb, const int* __restrict__ off,
    const int2* __restrict__ re, const float* __restrict__ comp,
    unsigned short* __restrict__ A1b) {
  const int tid = threadIdx.x;
  const int wv = tid >> 6, lane = tid & 63;
  const int n = blockIdx.x * 4 + wv;
  if (n >= NN) return;
  float2v acc[8];
#pragma unroll
  for (int b = 0; b < 8; b++) { acc[b][0] = 0.f; acc[b][1] = 0.f; }
  const int beg = __builtin_amdgcn_readfirstlane(off[n]);
  const int end = __builtin_amdgcn_readfirstlane(off[n + 1]);
  int idx = beg;
  for (; idx + 7 < end; idx += 8) {
    int rc[8]; float sc[8]; unsigned int xv[8];
#pragma unroll
    for (int u = 0; u < 8; u++) {
      int2 t = re[idx + u];
      rc[u] = __builtin_amdgcn_readfirstlane(t.x);
      sc[u] = __uint_as_float(__builtin_amdgcn_readfirstlane(t.y));
    }
#pragma unroll
    for (int u = 0; u < 8; u++)
      xv[u] = *(const unsigned int*)&xb[(size_t)(rc[u] & 16383) * D1 + lane * 2];
#pragma unroll
    for (int u = 0; u < 8; u++) {
      const float* cb = &comp[(rc[u] >> 14) * 8];
      float2v sx = mk2(sc[u] * bflo(xv[u]), sc[u] * bfhi(xv[u]));
#pragma unroll
      for (int b = 0; b < 8; b++)
        acc[b] = __builtin_elementwise_fma(mk2(cb[b], cb[b]), sx, acc[b]);
    }
  }
  for (; idx < end; idx++) {
    int2 t = re[idx];
    int rc = __builtin_amdgcn_readfirstlane(t.x);
    float sc = __uint_as_float(__builtin_amdgcn_readfirstlane(t.y));
    unsigned int xv = *(const unsigned int*)&xb[(size_t)(rc & 16383) * D1 + lane * 2];
    const float* cb = &comp[(rc >> 14) * 8];
    float2v sx = mk2(sc * bflo(xv), sc * bfhi(xv));
#pragma unroll
    for (int b = 0; b < 8; b++)
      acc[b] = __builtin_elementwise_fma(mk2(cb[b], cb[b]), sx, acc[b]);
  }
#pragma unroll
  for (int b = 0; b < 8; b++) {
    ushort2 o; o.x = f2bf(acc[b][0]); o.y = f2bf(acc[b][1]);
    *(ushort2*)&A1b[(size_t)n * 1024 + b * 128 + lane * 2] = o;
  }
}

// ---------------------------------------------------------------------------
// agg2e: one wave per node; same scalarized uniform-load structure.
// ---------------------------------------------------------------------------
__global__ __launch_bounds__(256) void agg2e_kernel(
    const unsigned short* __restrict__ hb, const int* __restrict__ off,
    const int2* __restrict__ re, const float* __restrict__ comp,
    unsigned short* __restrict__ A2b) {
  const int tid = threadIdx.x;
  const int wv = tid >> 6, lane = tid & 63;
  const int n = blockIdx.x * 4 + wv;
  if (n >= NN) return;
  float acc[8];
#pragma unroll
  for (int b = 0; b < 8; b++) acc[b] = 0.f;
  const int beg = __builtin_amdgcn_readfirstlane(off[n]);
  const int end = __builtin_amdgcn_readfirstlane(off[n + 1]);
  int idx = beg;
  for (; idx + 7 < end; idx += 8) {
    int rc[8]; float sc[8]; float hv[8];
#pragma unroll
    for (int u = 0; u < 8; u++) {
      int2 t = re[idx + u];
      rc[u] = __builtin_amdgcn_readfirstlane(t.x);
      sc[u] = __uint_as_float(__builtin_amdgcn_readfirstlane(t.y));
    }
#pragma unroll
    for (int u = 0; u < 8; u++)
      hv[u] = bf2f(hb[(size_t)(rc[u] & 16383) * D2 + lane]);
#pragma unroll
    for (int u = 0; u < 8; u++) {
      const float* cb = &comp[(rc[u] >> 14) * 8];
      float sh = sc[u] * hv[u];
#pragma unroll
      for (int b = 0; b < 8; b++) acc[b] = fmaf(cb[b], sh, acc[b]);
    }
  }
  for (; idx < end; idx++) {
    int2 t = re[idx];
    int rc = __builtin_amdgcn_readfirstlane(t.x);
    float sc = __uint_as_float(__builtin_amdgcn_readfirstlane(t.y));
    float hv = bf2f(hb[(size_t)(rc & 16383) * D2 + lane]);
    const float* cb = &comp[(rc >> 14) * 8];
    float sh = sc * hv;
#pragma unroll
    for (int b = 0; b < 8; b++) acc[b] = fmaf(cb[b], sh, acc[b]);
  }
#pragma unroll
  for (int b = 0; b < 8; b++)
    A2b[(size_t)n * 512 + b * 64 + lane] = f2bf(acc[b]);
}

// ---------------------------------------------------------------------------
// hlayer_v4: hb = bf16(relu([xb|A1b](K=1152) @ Wc1 + bias1))
// ---------------------------------------------------------------------------
__global__ __launch_bounds__(256) void hlayer_v4(
    const unsigned short* __restrict__ xb, const unsigned short* __restrict__ A1b,
    const unsigned short* __restrict__ Wf, const float* __restrict__ bias1,
    unsigned short* __restrict__ hb) {
  __shared__ unsigned short Hs[2][32 * 128];
  const int tid = threadIdx.x;
  const int wv = tid >> 6, lane = tid & 63;
  const int lrow = lane & 15, quad = lane >> 4;
  const int m0 = blockIdx.x * 32;
  const int mt = wv >> 1, nb = (wv & 1) * 2;

  int rgr[2], su4[2], sph[2];
#pragma unroll
  for (int p = 0; p < 2; p++) {
    int idx = tid + p * 256;
    int r = idx >> 4, u = idx & 15;
    int g = m0 + r;
    rgr[p] = g < NN ? g : NN - 1;
    su4[p] = u;
    sph[p] = r * 128 + ((u ^ (r & 15)) & 15) * 8;
  }

  const uint4* Bq = (const uint4*)Wf;
  uint4 rAe[2], rAo[2];
  uint4 B0[8], B1[8];
  float4e acc[2];
#pragma unroll
  for (int i = 0; i < 2; i++) {
    acc[i][0] = 0.f; acc[i][1] = 0.f; acc[i][2] = 0.f; acc[i][3] = 0.f;
  }

#define H_LDA(ra, t)                                                       \
  { int tc = (t) > 8 ? 8 : (t);                                            \
    _Pragma("unroll")                                                      \
    for (int p = 0; p < 2; p++) {                                          \
      const unsigned short* sp = (tc == 0)                                 \
          ? (xb + (size_t)rgr[p] * D1 + su4[p] * 8)                        \
          : (A1b + (size_t)rgr[p] * 1024 + (tc - 1) * 128 + su4[p] * 8);   \
      ra[p] = *(const uint4*)sp; } }
#define H_LDB(B, t)                                                        \
  { int tc = (t) > 8 ? 8 : (t);                                            \
    _Pragma("unroll")                                                      \
    for (int kk = 0; kk < 4; kk++) {                                       \
      int c = tc * 4 + kk;                                                 \
      B[2 * kk]     = Bq[(c * 4 + nb) * 64 + lane];                        \
      B[2 * kk + 1] = Bq[(c * 4 + nb + 1) * 64 + lane]; } }
#define H_STA(buf, ra)                                                     \
  { _Pragma("unroll")                                                      \
    for (int p = 0; p < 2; p++) *(uint4*)&Hs[buf][sph[p]] = ra[p]; }
#define H_CMP(buf, B)                                                      \
  { _Pragma("unroll")                                                      \
    for (int kk = 0; kk < 4; kk++) {                                       \
      uint4 af = *(const uint4*)&Hs[buf][(mt * 16 + lrow) * 128 +          \
                                         (((kk * 4 + quad) ^ lrow) & 15) * 8]; \
      acc[0] = bmm(af, B[2 * kk], acc[0]);                                 \
      acc[1] = bmm(af, B[2 * kk + 1], acc[1]); } }

  H_LDA(rAe, 0); H_LDB(B0, 0);
  H_LDA(rAo, 1);
  H_STA(0, rAe);
  H_LDB(B1, 1);
  H_LDA(rAe, 2);
  __syncthreads();

  for (int t = 0; t < 8; t += 2) {
    H_STA(1, rAo);
    H_LDA(rAo, t + 3);
    H_CMP(0, B0);
    H_LDB(B0, t + 2);
    __syncthreads();
    H_STA(0, rAe);
    H_LDA(rAe, t + 4);
    H_CMP(1, B1);
    H_LDB(B1, t + 3);
    __syncthreads();
  }
  H_CMP(0, B0);                                   // tile 8
#undef H_LDA
#undef H_LDB
#undef H_STA
#undef H_CMP

#pragma unroll
  for (int ntl = 0; ntl < 2; ntl++) {
    int col = (nb + ntl) * 16 + lrow;
    float bv = bias1[col];
#pragma unroll
    for (int j = 0; j < 4; j++) {
      int r = m0 + mt * 16 + quad * 4 + j;
      if (r < NN)
        hb[(size_t)r * D2 + col] = f2bf(fmaxf(acc[ntl][j] + bv, 0.f));
    }
  }
}

// ---------------------------------------------------------------------------
// out_v4: out = [hb|A2b](K=576) @ Wc2 + bias2
// ---------------------------------------------------------------------------
__global__ __launch_bounds__(128) void out_v4(
    const unsigned short* __restrict__ hb, const unsigned short* __restrict__ A2b,
    const unsigned short* __restrict__ Wf, const float* __restrict__ bias2,
    float* __restrict__ out) {
  __shared__ unsigned short Os[2][32 * 64];
  const int tid = threadIdx.x;
  const int wv = tid >> 6, lane = tid & 63;
  const int lrow = lane & 15, quad = lane >> 4;
  const int m0 = blockIdx.x * 32;

  int rgr[2], su4[2], sph[2];
#pragma unroll
  for (int p = 0; p < 2; p++) {
    int idx = tid + p * 128;
    int r = idx >> 3, u = idx & 7;
    int g = m0 + r;
    rgr[p] = g < NN ? g : NN - 1;
    su4[p] = u;
    sph[p] = r * 64 + ((u ^ (r & 7)) & 7) * 8;
  }

  const uint4* Bq = (const uint4*)Wf;
  uint4 rAe[2], rAo[2];
  uint4 B0[4], B1[4];
  float4e acc[2];
#pragma unroll
  for (int i = 0; i < 2; i++) {
    acc[i][0] = 0.f; acc[i][1] = 0.f; acc[i][2] = 0.f; acc[i][3] = 0.f;
  }

#define O_LDA(ra, t)                                                       \
  { int tc = (t) > 8 ? 8 : (t);                                            \
    _Pragma("unroll")                                                      \
    for (int p = 0; p < 2; p++) {                                          \
      const unsigned short* sp = (tc == 0)                                 \
          ? (hb + (size_t)rgr[p] * D2 + su4[p] * 8)                        \
          : (A2b + (size_t)rgr[p] * 512 + (tc - 1) * 64 + su4[p] * 8);     \
      ra[p] = *(const uint4*)sp; } }
#define O_LDB(B, t)                                                        \
  { int tc = (t) > 8 ? 8 : (t);                                            \
    _Pragma("unroll")                                                      \
    for (int kk = 0; kk < 2; kk++) {                                       \
      int c = tc * 2 + kk;                                                 \
      B[2 * kk]     = Bq[(c * 2) * 64 + lane];                             \
      B[2 * kk + 1] = Bq[(c * 2 + 1) * 64 + lane]; } }
#define O_STA(buf, ra)                                                     \
  { _Pragma("unroll")                                                      \
    for (int p = 0; p < 2; p++) *(uint4*)&Os[buf][sph[p]] = ra[p]; }
#define O_CMP(buf, B)                                                      \
  { _Pragma("unroll")                                                      \
    for (int kk = 0; kk < 2; kk++) {                                       \
      uint4 af = *(const uint4*)&Os[buf][(wv * 16 + lrow) * 64 +           \
                                         (((kk * 4 + quad) ^ lrow) & 7) * 8]; \
      acc[0] = bmm(af, B[2 * kk], acc[0]);                                 \
      acc[1] = bmm(af, B[2 * kk + 1], acc[1]); } }

  O_LDA(rAe, 0); O_LDB(B0, 0);
  O_LDA(rAo, 1);
  O_STA(0, rAe);
  O_LDB(B1, 1);
  O_LDA(rAe, 2);
  __syncthreads();

  for (int t = 0; t < 8; t += 2) {
    O_STA(1, rAo);
    O_LDA(rAo, t + 3);
    O_CMP(0, B0);
    O_LDB(B0, t + 2);
    __syncthreads();
    O_STA(0, rAe);
    O_LDA(rAe, t + 4);
    O_CMP(1, B1);
    O_LDB(B1, t + 3);
    __syncthreads();
  }
  O_CMP(0, B0);                                   // tile 8
#undef O_LDA
#undef O_LDB
#undef O_STA
#undef O_CMP

#pragma unroll
  for (int ntl = 0; ntl < 2; ntl++) {
    int col = ntl * 16 + lrow;
    if (col < D3) {
      float bv = bias2[col];
#pragma unroll
      for (int j = 0; j < 4; j++) {
        int r = m0 + wv * 16 + quad * 4 + j;
        if (r < NN)
          out[(size_t)r * D3 + col] = acc[ntl][j] + bv;
      }
    }
  }
}

// ---------------------------------------------------------------------------
extern "C" void kernel_launch(void* const* d_in, const int* in_sizes, int n_in,
                              void* d_out, int out_size, void* d_ws,
                              size_t ws_size, hipStream_t stream) {
  const float* x_drug = (const float*)d_in[0];
  const float* drug_w = (const float*)d_in[1];
  const int*   ei     = (const int*)d_in[2];
  const float* basis1 = (const float*)d_in[3];
  const float* comp1  = (const float*)d_in[4];
  const float* root1  = (const float*)d_in[5];
  const float* bias1  = (const float*)d_in[6];
  const float* basis2 = (const float*)d_in[7];
  const float* comp2  = (const float*)d_in[8];
  const float* root2  = (const float*)d_in[9];
  const float* bias2  = (const float*)d_in[10];
  float* out = (float*)d_out;

  float* ws = (float*)d_ws;
  int*   deg  = (int*)ws;                          // 1,000,000
  int*   cnt  = deg + 1000000;                     // 10,016
  int*   off  = cnt + 10016;                       // 10,016
  int*   cur  = off + 10016;                       // 10,016
  int2*  re   = (int2*)(cur + 10016);              // 500,000 int2 (1M ints)
  unsigned short* xb   = (unsigned short*)((int*)re + 1000000);    // 640,000 f
  unsigned short* hb   = (unsigned short*)((float*)xb + 640000);   // 320,000 f
  unsigned short* Bfw  = (unsigned short*)((float*)hb + 320000);   // 131,072 f
  unsigned short* Wf1  = (unsigned short*)((float*)Bfw + 131072);  // 36,864 f
  unsigned short* Wf2  = (unsigned short*)((float*)Wf1 + 36864);   // 9,216 f
  float* R1 = (float*)Wf2 + 9216;                  // aggregation buffers
  unsigned short* A1b = (unsigned short*)R1;       // 10,000 x 1024 bf16
  unsigned short* A2b = (unsigned short*)R1;       // aliases A1b (after hlayer)

  hipMemsetAsync(deg, 0, (size_t)1000000 * 4, stream);

  // CSR build + weight prep (fused first pass)
  prep_kernel<<<(NE + W0_SZ + W1_SZ + W2_SZ + 255) / 256, 256, 0, stream>>>(
      ei, deg, drug_w, Bfw, root1, basis1, Wf1, root2, basis2, Wf2);

  // gemm0 (needs Bfw) overlapped with cnt (needs deg) -- both from prep
  gemm0cnt<<<625 + 40, 256, 0, stream>>>(x_drug, Bfw, xb, deg, cnt);

  scan_kernel<<<1, 1024, 0, stream>>>(cnt, off, cur);
  scatter_kernel<<<(NE + 255) / 256, 256, 0, stream>>>(ei, deg, cur, re);

  // layer 1
  agg1e_kernel<<<(NN + 3) / 4, 256, 0, stream>>>(xb, off, re, comp1, A1b);
  hlayer_v4<<<(NN + 31) / 32, 256, 0, stream>>>(xb, A1b, Wf1, bias1, hb);

  // layer 2
  agg2e_kernel<<<(NN + 3) / 4, 256, 0, stream>>>(hb, off, re, comp2, A2b);
  out_v4<<<(NN + 31) / 32, 128, 0, stream>>>(hb, A2b, Wf2, bias2, out);
}

// Round 11
// 283.977 us; speedup vs baseline: 1.0241x; 1.0176x over previous
//
#include <hip/hip_runtime.h>

#define NN 10000    // nodes
#define RR 100      // relations
#define EE 5000     // edges per relation
#define D0 2048
#define D1 128
#define D2 64
#define D3 20
#define NE (RR*EE)  // 500000 edges total

using short8  = __attribute__((ext_vector_type(8))) short;
using float4e = __attribute__((ext_vector_type(4))) float;
using float2v = __attribute__((ext_vector_type(2))) float;

__device__ __forceinline__ unsigned short f2bf(float f) {
  unsigned int u = __float_as_uint(f);
  unsigned int r = u + 0x7fffu + ((u >> 16) & 1u);   // RNE
  return (unsigned short)(r >> 16);
}
__device__ __forceinline__ float bf2f(unsigned short u) {
  return __uint_as_float(((unsigned int)u) << 16);
}
__device__ __forceinline__ unsigned int pk2(float lo, float hi) {
  return ((unsigned int)f2bf(hi) << 16) | (unsigned int)f2bf(lo);
}
__device__ __forceinline__ float bflo(unsigned int u) {
  return __uint_as_float((u & 0xffffu) << 16);
}
__device__ __forceinline__ float bfhi(unsigned int u) {
  return __uint_as_float(u & 0xffff0000u);
}
__device__ __forceinline__ float2v mk2(float a, float b) {
  float2v v; v[0] = a; v[1] = b; return v;
}

// bf16x8 MFMA on uint4-typed fragments
__device__ __forceinline__ float4e bmm(uint4 a, uint4 b, float4e c) {
  return __builtin_amdgcn_mfma_f32_16x16x32_bf16(
      __builtin_bit_cast(short8, a), __builtin_bit_cast(short8, b), c, 0, 0, 0);
}

// ---------------------------------------------------------------------------
// fused prep: deg histogram + all three weight->bf16 fragment-layout packs
// ---------------------------------------------------------------------------
#define W0_SZ 262144   // drug_w frags: c 0..63, nt 0..7
#define W1_SZ 73728    // Wc1 frags:    c 0..35, nt 0..3
#define W2_SZ 18432    // Wc2 frags:    c 0..17, nt 0..1
__global__ void prep_kernel(const int* __restrict__ ei, int* __restrict__ deg,
                            const float* __restrict__ drug_w,
                            unsigned short* __restrict__ Bfw,
                            const float* __restrict__ root1,
                            const float* __restrict__ basis1,
                            unsigned short* __restrict__ Wf1,
                            const float* __restrict__ root2,
                            const float* __restrict__ basis2,
                            unsigned short* __restrict__ Wf2) {
  int gid = blockIdx.x * 256 + threadIdx.x;
  if (gid < NE) {
    int r = gid / EE, e = gid - r * EE;
    int d = ei[r * 2 * EE + EE + e];
    atomicAdd(&deg[r * NN + d], 1);
    return;
  }
  gid -= NE;
  if (gid < W0_SZ) {
    int j = gid & 7, lane = (gid >> 3) & 63, rest = gid >> 9;
    int nt = rest & 7, c = rest >> 3;
    int k = c * 32 + (lane >> 4) * 8 + j;
    int n = nt * 16 + (lane & 15);
    Bfw[gid] = f2bf(drug_w[(size_t)k * 128 + n]);
    return;
  }
  gid -= W0_SZ;
  if (gid < W1_SZ) {
    int j = gid & 7, lane = (gid >> 3) & 63, rest = gid >> 9;
    int nt = rest & 3, c = rest >> 2;
    int k = c * 32 + (lane >> 4) * 8 + j;
    int o = nt * 16 + (lane & 15);
    float v = (k < 128) ? root1[k * 64 + o] : basis1[(k - 128) * 64 + o];
    Wf1[gid] = f2bf(v);
    return;
  }
  gid -= W1_SZ;
  if (gid < W2_SZ) {
    int j = gid & 7, lane = (gid >> 3) & 63, rest = gid >> 9;
    int nt = rest & 1, c = rest >> 1;
    int k = c * 32 + (lane >> 4) * 8 + j;
    int cc = nt * 16 + (lane & 15);
    float v = 0.f;
    if (cc < 20) v = (k < 64) ? root2[k * 20 + cc] : basis2[(k - 64) * 20 + cc];
    Wf2[gid] = f2bf(v);
  }
}

// ---------------------------------------------------------------------------
// single-pass scan
// ---------------------------------------------------------------------------
__global__ __launch_bounds__(1024) void scan_kernel(const int* __restrict__ cnt,
                                                    int* __restrict__ off,
                                                    int* __restrict__ cur) {
  __shared__ int wsum[16];
  const int tid = threadIdx.x;
  const int wv = tid >> 6, lane = tid & 63;
  const bool act = tid < 1000;
  int loc[10];
  int s = 0;
  if (act) {
#pragma unroll
    for (int i = 0; i < 10; i++) { loc[i] = cnt[tid * 10 + i]; s += loc[i]; }
  }
  int ws = s;
#pragma unroll
  for (int d = 1; d < 64; d <<= 1) {
    int t = __shfl_up(ws, d, 64);
    if (lane >= d) ws += t;
  }
  if (lane == 63) wsum[wv] = ws;
  __syncthreads();
  if (wv == 0) {
    int w = (lane < 16) ? wsum[lane] : 0;
#pragma unroll
    for (int d = 1; d < 16; d <<= 1) {
      int t = __shfl_up(w, d, 64);
      if (lane >= d) w += t;
    }
    if (lane < 16) wsum[lane] = w;
  }
  __syncthreads();
  int excl = (wv ? wsum[wv - 1] : 0) + ws - s;
  if (act) {
    int run = excl;
#pragma unroll
    for (int i = 0; i < 10; i++) {
      off[tid * 10 + i] = run;
      cur[tid * 10 + i] = run;
      run += loc[i];
    }
  }
  if (tid == 1023) off[NN] = excl;   // s==0 for tid>=1000 -> excl == total
}

// re[p] = { (r<<14)|src , bits(1/max(deg,1)) }  -- one 8B record per edge
__global__ void scatter_kernel(const int* __restrict__ ei,
                               const int* __restrict__ deg,
                               int* __restrict__ cur, int2* __restrict__ re) {
  int gid = blockIdx.x * 256 + threadIdx.x;
  if (gid >= NE) return;
  int r = gid / EE, e = gid - r * EE;
  int s = ei[r * 2 * EE + e];
  int d = ei[r * 2 * EE + EE + e];
  int p = atomicAdd(&cur[d], 1);
  float escv = 1.0f / fmaxf((float)deg[r * NN + d], 1.0f);
  re[p] = make_int2((r << 14) | s, __float_as_int(escv));
}

// ---------------------------------------------------------------------------
// gemm0cnt: blocks 0..624 = gemm0 (M=16, N=128, EIGHT waves / 512 threads --
// ~19.5 waves/CU so cross-wave overlap hides barrier drains & L2 B latency;
// wave nw owns one 16-col ntile, 4 MFMA + 4 B-loads per K-tile; each thread
// stages exactly one float4 of A per tile). blocks 625..644 = cnt.
// ---------------------------------------------------------------------------
__global__ __launch_bounds__(512) void gemm0cnt(
    const float* __restrict__ A, const unsigned short* __restrict__ Bfw,
    unsigned short* __restrict__ xb, const int* __restrict__ deg,
    int* __restrict__ cnt) {
  if (blockIdx.x >= 625) {
    int n = (blockIdx.x - 625) * 512 + threadIdx.x;
    if (n < NN) {
      int s = 0;
      for (int r = 0; r < RR; r++) s += deg[r * NN + n];
      cnt[n] = s;
    }
    return;
  }
  __shared__ unsigned short As[2][16 * 128];
  const int tid = threadIdx.x;
  const int nw = tid >> 6, lane = tid & 63;        // nw 0..7
  const int lrow = lane & 15, quad = lane >> 4;
  const int m0 = blockIdx.x * 16;                  // 625*16 == 10000 exact

  // staging: thread covers row tid>>5 (0..15), float4 at (tid&31)*16B
  const int srow = tid >> 5, li = tid & 31;
  const float* ap = A + (size_t)(m0 + srow) * D0 + li * 4;
  const int wo = srow * 128 + (((li >> 1) ^ (srow & 15)) & 15) * 8 + (li & 1) * 4;

  const uint4* Bq = (const uint4*)Bfw;
  float4 rAe, rAo;
  uint4 B0[4], B1[4];
  float4e acc = {0.f, 0.f, 0.f, 0.f};

#define LDA(ra, t)                                                   \
  { int tc = (t) > 15 ? 15 : (t);                                    \
    ra = *(const float4*)(ap + tc * 128); }
#define LDB(B, t)                                                    \
  { int tc = (t) > 15 ? 15 : (t);                                    \
    _Pragma("unroll")                                                \
    for (int kk = 0; kk < 4; kk++)                                   \
      B[kk] = Bq[((tc * 4 + kk) * 8 + nw) * 64 + lane]; }
#define STA(buf, ra)                                                 \
  { uint2 u; u.x = pk2(ra.x, ra.y); u.y = pk2(ra.z, ra.w);           \
    *(uint2*)&As[buf][wo] = u; }
#define CMP(buf, B)                                                  \
  { _Pragma("unroll")                                                \
    for (int kk = 0; kk < 4; kk++) {                                 \
      uint4 af = *(const uint4*)&As[buf][lrow * 128 +                \
                                         (((kk * 4 + quad) ^ lrow) & 15) * 8]; \
      acc = bmm(af, B[kk], acc); } }

  LDA(rAe, 0); LDB(B0, 0);
  LDA(rAo, 1);
  STA(0, rAe);
  LDB(B1, 1);
  LDA(rAe, 2);
  __syncthreads();

  for (int t = 0; t < 16; t += 2) {
    STA(1, rAo);
    LDA(rAo, t + 3);
    CMP(0, B0);
    LDB(B0, t + 2);
    __syncthreads();
    STA(0, rAe);
    LDA(rAe, t + 4);
    CMP(1, B1);
    LDB(B1, t + 3);
    __syncthreads();
  }
#undef LDA
#undef LDB
#undef STA
#undef CMP

  const int c0 = nw * 16 + lrow;
#pragma unroll
  for (int j = 0; j < 4; j++) {
    int r = m0 + quad * 4 + j;
    xb[(size_t)r * D1 + c0] = f2bf(acc[j]);
  }
}

// ---------------------------------------------------------------------------
// agg1e: A1b[n, b*128+i] = bf16( sum_{e->n} esc_e*comp1[r_e,b]*x[src_e,i] )
// one wave per node; re records (8B, rec+esc packed) via scalarized uniform
// loads; comp rows via SGPR-based loads. (R8-proven)
// ---------------------------------------------------------------------------
__global__ __launch_bounds__(256) void agg1e_kernel(
    const unsigned short* __restrict__ xb, const int* __restrict__ off,
    const int2* __restrict__ re, const float* __restrict__ comp,
    unsigned short* __restrict__ A1b) {
  const int tid = threadIdx.x;
  const int wv = tid >> 6, lane = tid & 63;
  const int n = blockIdx.x * 4 + wv;
  if (n >= NN) return;
  float2v acc[8];
#pragma unroll
  for (int b = 0; b < 8; b++) { acc[b][0] = 0.f; acc[b][1] = 0.f; }
  const int beg = __builtin_amdgcn_readfirstlane(off[n]);
  const int end = __builtin_amdgcn_readfirstlane(off[n + 1]);
  int idx = beg;
  for (; idx + 7 < end; idx += 8) {
    int rc[8]; float sc[8]; unsigned int xv[8];
#pragma unroll
    for (int u = 0; u < 8; u++) {
      int2 t = re[idx + u];
      rc[u] = __builtin_amdgcn_readfirstlane(t.x);
      sc[u] = __uint_as_float(__builtin_amdgcn_readfirstlane(t.y));
    }
#pragma unroll
    for (int u = 0; u < 8; u++)
      xv[u] = *(const unsigned int*)&xb[(size_t)(rc[u] & 16383) * D1 + lane * 2];
#pragma unroll
    for (int u = 0; u < 8; u++) {
      const float* cb = &comp[(rc[u] >> 14) * 8];
      float2v sx = mk2(sc[u] * bflo(xv[u]), sc[u] * bfhi(xv[u]));
#pragma unroll
      for (int b = 0; b < 8; b++)
        acc[b] = __builtin_elementwise_fma(mk2(cb[b], cb[b]), sx, acc[b]);
    }
  }
  for (; idx < end; idx++) {
    int2 t = re[idx];
    int rc = __builtin_amdgcn_readfirstlane(t.x);
    float sc = __uint_as_float(__builtin_amdgcn_readfirstlane(t.y));
    unsigned int xv = *(const unsigned int*)&xb[(size_t)(rc & 16383) * D1 + lane * 2];
    const float* cb = &comp[(rc >> 14) * 8];
    float2v sx = mk2(sc * bflo(xv), sc * bfhi(xv));
#pragma unroll
    for (int b = 0; b < 8; b++)
      acc[b] = __builtin_elementwise_fma(mk2(cb[b], cb[b]), sx, acc[b]);
  }
#pragma unroll
  for (int b = 0; b < 8; b++) {
    ushort2 o; o.x = f2bf(acc[b][0]); o.y = f2bf(acc[b][1]);
    *(ushort2*)&A1b[(size_t)n * 1024 + b * 128 + lane * 2] = o;
  }
}

// ---------------------------------------------------------------------------
// agg2e: one wave per node; same scalarized uniform-load structure. (R8)
// ---------------------------------------------------------------------------
__global__ __launch_bounds__(256) void agg2e_kernel(
    const unsigned short* __restrict__ hb, const int* __restrict__ off,
    const int2* __restrict__ re, const float* __restrict__ comp,
    unsigned short* __restrict__ A2b) {
  const int tid = threadIdx.x;
  const int wv = tid >> 6, lane = tid & 63;
  const int n = blockIdx.x * 4 + wv;
  if (n >= NN) return;
  float acc[8];
#pragma unroll
  for (int b = 0; b < 8; b++) acc[b] = 0.f;
  const int beg = __builtin_amdgcn_readfirstlane(off[n]);
  const int end = __builtin_amdgcn_readfirstlane(off[n + 1]);
  int idx = beg;
  for (; idx + 7 < end; idx += 8) {
    int rc[8]; float sc[8]; float hv[8];
#pragma unroll
    for (int u = 0; u < 8; u++) {
      int2 t = re[idx + u];
      rc[u] = __builtin_amdgcn_readfirstlane(t.x);
      sc[u] = __uint_as_float(__builtin_amdgcn_readfirstlane(t.y));
    }
#pragma unroll
    for (int u = 0; u < 8; u++)
      hv[u] = bf2f(hb[(size_t)(rc[u] & 16383) * D2 + lane]);
#pragma unroll
    for (int u = 0; u < 8; u++) {
      const float* cb = &comp[(rc[u] >> 14) * 8];
      float sh = sc[u] * hv[u];
#pragma unroll
      for (int b = 0; b < 8; b++) acc[b] = fmaf(cb[b], sh, acc[b]);
    }
  }
  for (; idx < end; idx++) {
    int2 t = re[idx];
    int rc = __builtin_amdgcn_readfirstlane(t.x);
    float sc = __uint_as_float(__builtin_amdgcn_readfirstlane(t.y));
    float hv = bf2f(hb[(size_t)(rc & 16383) * D2 + lane]);
    const float* cb = &comp[(rc >> 14) * 8];
    float sh = sc * hv;
#pragma unroll
    for (int b = 0; b < 8; b++) acc[b] = fmaf(cb[b], sh, acc[b]);
  }
#pragma unroll
  for (int b = 0; b < 8; b++)
    A2b[(size_t)n * 512 + b * 64 + lane] = f2bf(acc[b]);
}

// ---------------------------------------------------------------------------
// hlayer_v4: hb = bf16(relu([xb|A1b](K=1152) @ Wc1 + bias1))
// ---------------------------------------------------------------------------
__global__ __launch_bounds__(256) void hlayer_v4(
    const unsigned short* __restrict__ xb, const unsigned short* __restrict__ A1b,
    const unsigned short* __restrict__ Wf, const float* __restrict__ bias1,
    unsigned short* __restrict__ hb) {
  __shared__ unsigned short Hs[2][32 * 128];
  const int tid = threadIdx.x;
  const int wv = tid >> 6, lane = tid & 63;
  const int lrow = lane & 15, quad = lane >> 4;
  const int m0 = blockIdx.x * 32;
  const int mt = wv >> 1, nb = (wv & 1) * 2;

  int rgr[2], su4[2], sph[2];
#pragma unroll
  for (int p = 0; p < 2; p++) {
    int idx = tid + p * 256;
    int r = idx >> 4, u = idx & 15;
    int g = m0 + r;
    rgr[p] = g < NN ? g : NN - 1;
    su4[p] = u;
    sph[p] = r * 128 + ((u ^ (r & 15)) & 15) * 8;
  }

  const uint4* Bq = (const uint4*)Wf;
  uint4 rAe[2], rAo[2];
  uint4 B0[8], B1[8];
  float4e acc[2];
#pragma unroll
  for (int i = 0; i < 2; i++) {
    acc[i][0] = 0.f; acc[i][1] = 0.f; acc[i][2] = 0.f; acc[i][3] = 0.f;
  }

#define H_LDA(ra, t)                                                       \
  { int tc = (t) > 8 ? 8 : (t);                                            \
    _Pragma("unroll")                                                      \
    for (int p = 0; p < 2; p++) {                                          \
      const unsigned short* sp = (tc == 0)                                 \
          ? (xb + (size_t)rgr[p] * D1 + su4[p] * 8)                        \
          : (A1b + (size_t)rgr[p] * 1024 + (tc - 1) * 128 + su4[p] * 8);   \
      ra[p] = *(const uint4*)sp; } }
#define H_LDB(B, t)                                                        \
  { int tc = (t) > 8 ? 8 : (t);                                            \
    _Pragma("unroll")                                                      \
    for (int kk = 0; kk < 4; kk++) {                                       \
      int c = tc * 4 + kk;                                                 \
      B[2 * kk]     = Bq[(c * 4 + nb) * 64 + lane];                        \
      B[2 * kk + 1] = Bq[(c * 4 + nb + 1) * 64 + lane]; } }
#define H_STA(buf, ra)                                                     \
  { _Pragma("unroll")                                                      \
    for (int p = 0; p < 2; p++) *(uint4*)&Hs[buf][sph[p]] = ra[p]; }
#define H_CMP(buf, B)                                                      \
  { _Pragma("unroll")                                                      \
    for (int kk = 0; kk < 4; kk++) {                                       \
      uint4 af = *(const uint4*)&Hs[buf][(mt * 16 + lrow) * 128 +          \
                                         (((kk * 4 + quad) ^ lrow) & 15) * 8]; \
      acc[0] = bmm(af, B[2 * kk], acc[0]);                                 \
      acc[1] = bmm(af, B[2 * kk + 1], acc[1]); } }

  H_LDA(rAe, 0); H_LDB(B0, 0);
  H_LDA(rAo, 1);
  H_STA(0, rAe);
  H_LDB(B1, 1);
  H_LDA(rAe, 2);
  __syncthreads();

  for (int t = 0; t < 8; t += 2) {
    H_STA(1, rAo);
    H_LDA(rAo, t + 3);
    H_CMP(0, B0);
    H_LDB(B0, t + 2);
    __syncthreads();
    H_STA(0, rAe);
    H_LDA(rAe, t + 4);
    H_CMP(1, B1);
    H_LDB(B1, t + 3);
    __syncthreads();
  }
  H_CMP(0, B0);                                   // tile 8
#undef H_LDA
#undef H_LDB
#undef H_STA
#undef H_CMP

#pragma unroll
  for (int ntl = 0; ntl < 2; ntl++) {
    int col = (nb + ntl) * 16 + lrow;
    float bv = bias1[col];
#pragma unroll
    for (int j = 0; j < 4; j++) {
      int r = m0 + mt * 16 + quad * 4 + j;
      if (r < NN)
        hb[(size_t)r * D2 + col] = f2bf(fmaxf(acc[ntl][j] + bv, 0.f));
    }
  }
}

// ---------------------------------------------------------------------------
// out_v4: out = [hb|A2b](K=576) @ Wc2 + bias2
// ---------------------------------------------------------------------------
__global__ __launch_bounds__(128) void out_v4(
    const unsigned short* __restrict__ hb, const unsigned short* __restrict__ A2b,
    const unsigned short* __restrict__ Wf, const float* __restrict__ bias2,
    float* __restrict__ out) {
  __shared__ unsigned short Os[2][32 * 64];
  const int tid = threadIdx.x;
  const int wv = tid >> 6, lane = tid & 63;
  const int lrow = lane & 15, quad = lane >> 4;
  const int m0 = blockIdx.x * 32;

  int rgr[2], su4[2], sph[2];
#pragma unroll
  for (int p = 0; p < 2; p++) {
    int idx = tid + p * 128;
    int r = idx >> 3, u = idx & 7;
    int g = m0 + r;
    rgr[p] = g < NN ? g : NN - 1;
    su4[p] = u;
    sph[p] = r * 64 + ((u ^ (r & 7)) & 7) * 8;
  }

  const uint4* Bq = (const uint4*)Wf;
  uint4 rAe[2], rAo[2];
  uint4 B0[4], B1[4];
  float4e acc[2];
#pragma unroll
  for (int i = 0; i < 2; i++) {
    acc[i][0] = 0.f; acc[i][1] = 0.f; acc[i][2] = 0.f; acc[i][3] = 0.f;
  }

#define O_LDA(ra, t)                                                       \
  { int tc = (t) > 8 ? 8 : (t);                                            \
    _Pragma("unroll")                                                      \
    for (int p = 0; p < 2; p++) {                                          \
      const unsigned short* sp = (tc == 0)                                 \
          ? (hb + (size_t)rgr[p] * D2 + su4[p] * 8)                        \
          : (A2b + (size_t)rgr[p] * 512 + (tc - 1) * 64 + su4[p] * 8);     \
      ra[p] = *(const uint4*)sp; } }
#define O_LDB(B, t)                                                        \
  { int tc = (t) > 8 ? 8 : (t);                                            \
    _Pragma("unroll")                                                      \
    for (int kk = 0; kk < 2; kk++) {                                       \
      int c = tc * 2 + kk;                                                 \
      B[2 * kk]     = Bq[(c * 2) * 64 + lane];                             \
      B[2 * kk + 1] = Bq[(c * 2 + 1) * 64 + lane]; } }
#define O_STA(buf, ra)                                                     \
  { _Pragma("unroll")                                                      \
    for (int p = 0; p < 2; p++) *(uint4*)&Os[buf][sph[p]] = ra[p]; }
#define O_CMP(buf, B)                                                      \
  { _Pragma("unroll")                                                      \
    for (int kk = 0; kk < 2; kk++) {                                       \
      uint4 af = *(const uint4*)&Os[buf][(wv * 16 + lrow) * 64 +           \
                                         (((kk * 4 + quad) ^ lrow) & 7) * 8]; \
      acc[0] = bmm(af, B[2 * kk], acc[0]);                                 \
      acc[1] = bmm(af, B[2 * kk + 1], acc[1]); } }

  O_LDA(rAe, 0); O_LDB(B0, 0);
  O_LDA(rAo, 1);
  O_STA(0, rAe);
  O_LDB(B1, 1);
  O_LDA(rAe, 2);
  __syncthreads();

  for (int t = 0; t < 8; t += 2) {
    O_STA(1, rAo);
    O_LDA(rAo, t + 3);
    O_CMP(0, B0);
    O_LDB(B0, t + 2);
    __syncthreads();
    O_STA(0, rAe);
    O_LDA(rAe, t + 4);
    O_CMP(1, B1);
    O_LDB(B1, t + 3);
    __syncthreads();
  }
  O_CMP(0, B0);                                   // tile 8
#undef O_LDA
#undef O_LDB
#undef O_STA
#undef O_CMP

#pragma unroll
  for (int ntl = 0; ntl < 2; ntl++) {
    int col = ntl * 16 + lrow;
    if (col < D3) {
      float bv = bias2[col];
#pragma unroll
      for (int j = 0; j < 4; j++) {
        int r = m0 + wv * 16 + quad * 4 + j;
        if (r < NN)
          out[(size_t)r * D3 + col] = acc[ntl][j] + bv;
      }
    }
  }
}

// ---------------------------------------------------------------------------
extern "C" void kernel_launch(void* const* d_in, const int* in_sizes, int n_in,
                              void* d_out, int out_size, void* d_ws,
                              size_t ws_size, hipStream_t stream) {
  const float* x_drug = (const float*)d_in[0];
  const float* drug_w = (const float*)d_in[1];
  const int*   ei     = (const int*)d_in[2];
  const float* basis1 = (const float*)d_in[3];
  const float* comp1  = (const float*)d_in[4];
  const float* root1  = (const float*)d_in[5];
  const float* bias1  = (const float*)d_in[6];
  const float* basis2 = (const float*)d_in[7];
  const float* comp2  = (const float*)d_in[8];
  const float* root2  = (const float*)d_in[9];
  const float* bias2  = (const float*)d_in[10];
  float* out = (float*)d_out;

  float* ws = (float*)d_ws;
  int*   deg  = (int*)ws;                          // 1,000,000
  int*   cnt  = deg + 1000000;                     // 10,016
  int*   off  = cnt + 10016;                       // 10,016
  int*   cur  = off + 10016;                       // 10,016
  int2*  re   = (int2*)(cur + 10016);              // 500,000 int2 (1M ints)
  unsigned short* xb   = (unsigned short*)((int*)re + 1000000);    // 640,000 f
  unsigned short* hb   = (unsigned short*)((float*)xb + 640000);   // 320,000 f
  unsigned short* Bfw  = (unsigned short*)((float*)hb + 320000);   // 131,072 f
  unsigned short* Wf1  = (unsigned short*)((float*)Bfw + 131072);  // 36,864 f
  unsigned short* Wf2  = (unsigned short*)((float*)Wf1 + 36864);   // 9,216 f
  float* R1 = (float*)Wf2 + 9216;                  // aggregation buffers
  unsigned short* A1b = (unsigned short*)R1;       // 10,000 x 1024 bf16
  unsigned short* A2b = (unsigned short*)R1;       // aliases A1b (after hlayer)

  hipMemsetAsync(deg, 0, (size_t)1000000 * 4, stream);

  // CSR build + weight prep (fused first pass)
  prep_kernel<<<(NE + W0_SZ + W1_SZ + W2_SZ + 255) / 256, 256, 0, stream>>>(
      ei, deg, drug_w, Bfw, root1, basis1, Wf1, root2, basis2, Wf2);

  // gemm0 (needs Bfw) overlapped with cnt (needs deg) -- both from prep
  gemm0cnt<<<625 + 20, 512, 0, stream>>>(x_drug, Bfw, xb, deg, cnt);

  scan_kernel<<<1, 1024, 0, stream>>>(cnt, off, cur);
  scatter_kernel<<<(NE + 255) / 256, 256, 0, stream>>>(ei, deg, cur, re);

  // layer 1
  agg1e_kernel<<<(NN + 3) / 4, 256, 0, stream>>>(xb, off, re, comp1, A1b);
  hlayer_v4<<<(NN + 31) / 32, 256, 0, stream>>>(xb, A1b, Wf1, bias1, hb);

  // layer 2
  agg2e_kernel<<<(NN + 3) / 4, 256, 0, stream>>>(hb, off, re, comp2, A2b);
  out_v4<<<(NN + 31) / 32, 128, 0, stream>>>(hb, A2b, Wf2, bias2, out);
}